// Round 5
// baseline (377.075 us; speedup 1.0000x reference)
//
#include <hip/hip_runtime.h>
#include <hip/hip_bf16.h>

typedef __attribute__((ext_vector_type(8))) short s16x8;
typedef __attribute__((ext_vector_type(4))) float f32x4;
typedef __attribute__((ext_vector_type(16))) float f32x16;
typedef __attribute__((ext_vector_type(4))) unsigned short us4;
typedef __attribute__((ext_vector_type(4))) unsigned int u32x4;

#define MFMA16(a,b,c) __builtin_amdgcn_mfma_f32_16x16x32_bf16((a),(b),(c),0,0,0)
#define MFMA32(a,b,c) __builtin_amdgcn_mfma_f32_32x32x16_bf16((a),(b),(c),0,0,0)

__device__ __forceinline__ float b2f(unsigned short u){
  union{unsigned u; float f;} v; v.u = ((unsigned)u)<<16; return v.f;
}
__device__ __forceinline__ unsigned short f2b(float f){
  union{float f; unsigned u;} v; v.f = f;
  unsigned r = v.u + 0x7fffu + ((v.u>>16)&1u);
  return (unsigned short)(r>>16);
}

__device__ __forceinline__ void gl_lds16(const void* gp, void* lp){
  __builtin_amdgcn_global_load_lds((const __attribute__((address_space(1))) void*)gp,
                                   (__attribute__((address_space(3))) void*)lp, 16, 0, 0);
}

// ---- 256-thread staging helpers ----
__device__ __forceinline__ void stage_64x256(void* lds, const unsigned short* g, int stride){
  const int t = threadIdx.x, wv = t>>6;
  #pragma unroll
  for (int i=0;i<8;++i){
    int ch = i*256 + t;
    int row = ch>>5, cc = ch&31, sc = cc ^ (row&7);
    gl_lds16((const char*)(g + (size_t)row*stride) + sc*16,
             (char*)lds + (((size_t)i*256 + wv*64)<<4));
  }
}
__device__ __forceinline__ void stage_256x64(void* lds, const unsigned short* g){
  const int t = threadIdx.x, wv = t>>6;
  #pragma unroll
  for (int i=0;i<8;++i){
    int ch = i*256 + t;
    int row = ch>>3, cc = ch&7, sc = cc ^ (row&7);
    gl_lds16((const char*)(g + (size_t)row*4096) + sc*16,
             (char*)lds + (((size_t)i*256 + wv*64)<<4));
  }
}

// ---------------- f32 -> bf16 cast ----------------
__global__ void k_cvt(const float* __restrict__ src, unsigned short* __restrict__ dst){
  int i = blockIdx.x*256 + threadIdx.x;
  f32x4 v = *(const f32x4*)(src + (size_t)i*4);
  us4 o;
  #pragma unroll
  for (int r=0;r<4;++r) o[r] = f2b(v[r]);
  *(us4*)(dst + (size_t)i*4) = o;
}

// ---------------- density chain (all f32) ----------------
__global__ void k_gray(const float* __restrict__ xg, float* __restrict__ gray){
  int b = blockIdx.y, n = blockIdx.x*256 + threadIdx.x;
  const float* p = xg + (size_t)b*256*4096 + n;
  float s0=0,s1=0,s2=0,s3=0;
  for (int c=0;c<256;c+=4){
    s0 += p[(size_t)c*4096];
    s1 += p[(size_t)(c+1)*4096];
    s2 += p[(size_t)(c+2)*4096];
    s3 += p[(size_t)(c+3)*4096];
  }
  gray[b*4096+n] = (s0+s1+s2+s3)*(1.f/256.f);
}

__global__ void k_lapabs(const float* __restrict__ gray, float* __restrict__ labs){
  int b = blockIdx.y, n = blockIdx.x*256 + threadIdx.x;
  int hh = n>>6, ww = n&63;
  const float* g = gray + b*4096;
  float c = g[n];
  float up = hh>0  ? g[n-64] : 0.f;
  float dn = hh<63 ? g[n+64] : 0.f;
  float lf = ww>0  ? g[n-1]  : 0.f;
  float rt = ww<63 ? g[n+1]  : 0.f;
  labs[b*4096+n] = fabsf(4.f*c - up - dn - lf - rt);
}

__global__ void k_h8(const float* __restrict__ labs, const float* __restrict__ w1,
                     const float* __restrict__ b1, float* __restrict__ hbuf){
  int b = blockIdx.y, n = blockIdx.x*256 + threadIdx.x;
  int hh = n>>6, ww = n&63;
  const float* L = labs + b*4096;
  float tap[9];
  #pragma unroll
  for (int dy=-1;dy<=1;++dy)
    #pragma unroll
    for (int dx=-1;dx<=1;++dx){
      int y=hh+dy, x2=ww+dx;
      tap[(dy+1)*3+dx+1] = (y>=0&&y<64&&x2>=0&&x2<64)? L[y*64+x2] : 0.f;
    }
  #pragma unroll
  for (int j=0;j<8;++j){
    float a = b1[j];
    #pragma unroll
    for (int k=0;k<9;++k) a += w1[j*9+k]*tap[k];
    hbuf[((size_t)(b*8+j))*4096 + n] = fmaxf(a, 0.f);
  }
}

__global__ void k_scale(const float* __restrict__ hbuf, const float* __restrict__ w2,
                        const float* __restrict__ b2_, float* __restrict__ sc){
  int b = blockIdx.y, n = blockIdx.x*256 + threadIdx.x;
  int hh = n>>6, ww = n&63;
  float a = b2_[0];
  #pragma unroll
  for (int j=0;j<8;++j){
    const float* H = hbuf + ((size_t)(b*8+j))*4096;
    #pragma unroll
    for (int dy=-1;dy<=1;++dy)
      #pragma unroll
      for (int dx=-1;dx<=1;++dx){
        int y=hh+dy, x2=ww+dx;
        if (y>=0&&y<64&&x2>=0&&x2<64) a += w2[j*9+(dy+1)*3+(dx+1)]*H[y*64+x2];
      }
  }
  float sig = 1.f/(1.f+__expf(-a));
  sc[b*4096+n] = 0.0625f/(3.f - 2.f*sig);   // C^-0.5 / (1 + 2*(1-sig))
}

// ---------------- transpose+cast x[b][c][n] (f32) -> Xt[b][n][c] (bf16) ----------------
__global__ void k_transpose(const float* __restrict__ xg, unsigned short* __restrict__ Xtg){
  __shared__ unsigned short T[64*68];
  const int nb = blockIdx.x, cb = blockIdx.y, b = blockIdx.z;
  const int n0 = nb*64, c0 = cb*64;
  const int t = threadIdx.x;
  #pragma unroll
  for (int i=0;i<4;++i){
    int idx = i*256 + t;
    int c = idx>>4, k4 = idx&15;
    f32x4 v = *(const f32x4*)(xg + ((size_t)(b*256 + c0 + c))*4096 + n0 + k4*4);
    us4 o;
    #pragma unroll
    for (int r=0;r<4;++r) o[r] = f2b(v[r]);
    *(us4*)&T[c*68 + k4*4] = o;
  }
  __syncthreads();
  #pragma unroll
  for (int i=0;i<2;++i){
    int idx = i*256 + t;
    int n = idx>>3, ck = idx&7;
    unsigned short vv[8];
    #pragma unroll
    for (int j=0;j<8;++j) vv[j] = T[(ck*8+j)*68 + n];
    *(u32x4*)(Xtg + ((size_t)(b*4096 + n0 + n))*256 + c0 + ck*8) = *(const u32x4*)vv;
  }
}

// ---------------- QKV GEMM: D[o][n] = qkv_w[o][c] * Xt[n][c]^T ----------------
__global__ __launch_bounds__(256,2) void k_gemm_qkv(const unsigned short* __restrict__ Wg,
    const unsigned short* __restrict__ Xtg, const float* __restrict__ biasg,
    unsigned short* __restrict__ Qo, unsigned short* __restrict__ Ko, unsigned short* __restrict__ Vto){
  __shared__ unsigned short Wl[64*256], Xl[64*256];
  const int nt_ = blockIdx.x, at = blockIdx.y, b = blockIdx.z;
  const int a0 = at*64, n0 = nt_*64;
  stage_64x256(Wl, Wg + (size_t)a0*256, 256);
  stage_64x256(Xl, Xtg + ((size_t)(b*4096 + n0))*256, 256);
  __syncthreads();
  const int t = threadIdx.x, w = t>>6, lane = t&63, lam = lane&15, lg = lane>>4;
  f32x4 zz = {0.f,0.f,0.f,0.f};
  f32x4 acc[4] = {zz,zz,zz,zz};
  #pragma unroll
  for (int u=0;u<8;++u){
    int ar = 16*w + lam;
    s16x8 af = *(const s16x8*)((const char*)Wl + ar*512 + ((64*u+16*lg) ^ ((ar&7)<<4)));
    #pragma unroll
    for (int ct=0;ct<4;++ct){
      int br = 16*ct + lam;
      s16x8 bf = *(const s16x8*)((const char*)Xl + br*512 + ((64*u+16*lg) ^ ((br&7)<<4)));
      acc[ct] = MFMA16(af, bf, acc[ct]);
    }
  }
  const int ob = a0 + 16*w + 4*lg;
  f32x4 bias4 = *(const f32x4*)(biasg + ob);
  #pragma unroll
  for (int ct=0;ct<4;++ct){
    int n = n0 + 16*ct + lam;
    us4 ov;
    #pragma unroll
    for (int r=0;r<4;++r) ov[r] = f2b(acc[ct][r] + bias4[r]);
    if (a0 < 256){
      *(us4*)(Qo + ((size_t)(b*4096 + n))*256 + ob) = ov;        // Q[n][c]
    } else if (a0 < 512){
      *(us4*)(Ko + ((size_t)(b*4096 + n))*256 + (ob-256)) = ov;  // K[m][c]
    } else {
      #pragma unroll
      for (int r=0;r<4;++r)
        Vto[((size_t)(b*256 + (ob-512+r)))*4096 + n] = ov[r];    // Vt[c][m]
    }
  }
}

// ---------------- flash attention: 4 waves x 32 q-rows, 32x32x16 MFMA ----------------
__global__ __launch_bounds__(256,1) void k_attn(const unsigned short* __restrict__ Qg,
    const unsigned short* __restrict__ Kg, const unsigned short* __restrict__ Vtg,
    const float* __restrict__ Sg, unsigned short* __restrict__ AOt){
  __shared__ unsigned short Kl[2][64*256];               // 2 x 32KB
  __shared__ unsigned short Vl[2][256*64];               // 2 x 32KB
  __shared__ __align__(16) unsigned short Pl[4][32*64];  // 4 x 8KB... (32 rows x 128B)

  const int t = threadIdx.x, w = t>>6, lane = t&63, l31 = lane&31, h = lane>>5;
  const int bid = blockIdx.x;
  const int b = bid&7, qt = bid>>3;       // XCD-major: batch pinned to XCD
  const int qbase = qt*128 + w*32;

  // Q fragments: B-operand of 32x32x16. lane: q-col=l31, k-elems 16u+8h..+7
  s16x8 qf[16];
  {
    const unsigned short* qp = Qg + ((size_t)(b*4096 + qbase + l31))*256 + 8*h;
    #pragma unroll
    for (int u=0;u<16;++u) qf[u] = *(const s16x8*)(qp + 16*u);
  }
  f32x16 st0, st1, oa[8];
  #pragma unroll
  for (int i=0;i<16;++i){ st0[i]=0.f; st1[i]=0.f; }
  #pragma unroll
  for (int nb=0;nb<8;++nb)
    #pragma unroll
    for (int i=0;i<16;++i) oa[nb][i]=0.f;
  float m_run = -1.0e30f, l_run = 0.f;

  const unsigned short* Kb = Kg + (size_t)b*4096*256;
  const unsigned short* Vb = Vtg + (size_t)b*256*4096;
  const float* Sb = Sg + (size_t)b*4096;

  // row index of acc-reg r (C/D layout of 32x32): (r&3)+8*(r>>2)+4*h
  // prologue: stage tile 0
  stage_64x256(&Kl[0][0], Kb, 256);
  stage_256x64(&Vl[0][0], Vb);
  __syncthreads();

  int cur = 0;
  for (int kt=0; kt<64; ++kt){
    const int m0 = kt*64;
    if (kt < 63){
      stage_64x256(&Kl[cur^1][0], Kb + (size_t)(m0+64)*256, 256);
      stage_256x64(&Vl[cur^1][0], Vb + (m0+64));
    }
    const char* Kc = (const char*)&Kl[cur][0];
    const char* Vc = (const char*)&Vl[cur][0];

    // S^T = K * Q^T : st0 = keys 0..31, st1 = keys 32..63 (D: col=q=l31, row=key)
    #pragma unroll
    for (int i=0;i<16;++i){ st0[i]=0.f; st1[i]=0.f; }
    __builtin_amdgcn_s_setprio(1);
    #pragma unroll
    for (int u=0;u<16;++u){
      int off = (32*u + 16*h) ^ ((l31&7)<<4);
      s16x8 kf0 = *(const s16x8*)(Kc + l31*512 + off);
      s16x8 kf1 = *(const s16x8*)(Kc + (32+l31)*512 + off);
      st0 = MFMA32(kf0, qf[u], st0);
      st1 = MFMA32(kf1, qf[u], st1);
    }
    __builtin_amdgcn_s_setprio(0);

    // scales: st0 reg 4j+i -> key m = 8j+4h+i ; st1: +32
    float pm[32];
    {
      #pragma unroll
      for (int j=0;j<4;++j){
        f32x4 sv = *(const f32x4*)(Sb + m0 + 8*j + 4*h);
        #pragma unroll
        for (int i=0;i<4;++i) pm[4*j+i] = st0[4*j+i]*sv[i];
      }
      #pragma unroll
      for (int j=0;j<4;++j){
        f32x4 sv = *(const f32x4*)(Sb + m0 + 32 + 8*j + 4*h);
        #pragma unroll
        for (int i=0;i<4;++i) pm[16+4*j+i] = st1[4*j+i]*sv[i];
      }
    }
    // max tree (depth 5)
    float mx[16];
    #pragma unroll
    for (int i=0;i<16;++i) mx[i] = fmaxf(pm[i], pm[16+i]);
    #pragma unroll
    for (int i=0;i<8;++i) mx[i] = fmaxf(mx[i], mx[8+i]);
    #pragma unroll
    for (int i=0;i<4;++i) mx[i] = fmaxf(mx[i], mx[4+i]);
    float tmax = fmaxf(fmaxf(mx[0],mx[1]), fmaxf(mx[2],mx[3]));
    tmax = fmaxf(tmax, __shfl_xor(tmax, 32));
    float mnew = fmaxf(m_run, tmax);
    float fs = __expf(m_run - mnew);
    // exp + sum tree
    float sm[16];
    #pragma unroll
    for (int i=0;i<32;++i) pm[i] = __expf(pm[i]-mnew);
    #pragma unroll
    for (int i=0;i<16;++i) sm[i] = pm[i] + pm[16+i];
    #pragma unroll
    for (int i=0;i<8;++i) sm[i] += sm[8+i];
    #pragma unroll
    for (int i=0;i<4;++i) sm[i] += sm[4+i];
    float rsum = (sm[0]+sm[1]) + (sm[2]+sm[3]);
    rsum += __shfl_xor(rsum, 32);
    l_run = l_run*fs + rsum; m_run = mnew;

    // P -> per-wave LDS: row q=l31 (128B), m-offset XOR-swizzled
    #pragma unroll
    for (int j=0;j<4;++j){
      us4 pk0, pk1;
      #pragma unroll
      for (int i=0;i<4;++i){ pk0[i] = f2b(pm[4*j+i]); pk1[i] = f2b(pm[16+4*j+i]); }
      char* base = (char*)&Pl[w][0] + l31*128;
      *(us4*)(base + ((16*j + 8*h) ^ ((l31&7)<<4))) = pk0;        // m = 8j+4h..+3
      *(us4*)(base + ((64 + 16*j + 8*h) ^ ((l31&7)<<4))) = pk1;   // m = 32+8j+4h..+3
    }
    // rescale O: factor per acc-row q
    float fr[16];
    #pragma unroll
    for (int r=0;r<16;++r) fr[r] = __shfl(fs, (r&3)+8*(r>>2)+4*h);
    #pragma unroll
    for (int nb=0;nb<8;++nb)
      #pragma unroll
      for (int r=0;r<16;++r) oa[nb][r] *= fr[r];

    // PV: A=P[32q x 16m], B=V^T[16m x 32c]
    __builtin_amdgcn_s_setprio(1);
    #pragma unroll
    for (int ks=0;ks<4;++ks){
      s16x8 pa = *(const s16x8*)((const char*)&Pl[w][0] + l31*128 + ((32*ks + 16*h) ^ ((l31&7)<<4)));
      #pragma unroll
      for (int nb=0;nb<8;++nb){
        int c = 32*nb + l31;
        s16x8 vf = *(const s16x8*)(Vc + c*128 + ((32*ks + 16*h) ^ ((c&7)<<4)));
        oa[nb] = MFMA32(pa, vf, oa[nb]);
      }
    }
    __builtin_amdgcn_s_setprio(0);

    __syncthreads();   // all waves done reading buf[cur]; next-tile stages drained
    cur ^= 1;
  }
  // epilogue: normalize rows, write AOt[n][c]
  float li = 1.f/l_run;
  float lr[16];
  #pragma unroll
  for (int r=0;r<16;++r) lr[r] = __shfl(li, (r&3)+8*(r>>2)+4*h);
  #pragma unroll
  for (int nb=0;nb<8;++nb){
    #pragma unroll
    for (int r=0;r<16;++r){
      int qr = (r&3)+8*(r>>2)+4*h;
      AOt[((size_t)(b*4096 + qbase + qr))*256 + 32*nb + l31] = f2b(oa[nb][r]*lr[r]);
    }
  }
}

// ---------------- OUT GEMM: out[o][n] = AOt[n][c]*out_w[o][c]^T + bias + x (f32 out) ----------------
__global__ __launch_bounds__(256,2) void k_gemm_out(const unsigned short* __restrict__ Ag,
    const unsigned short* __restrict__ Bg, const float* __restrict__ biasg,
    const float* __restrict__ xg, float* __restrict__ outg){
  __shared__ unsigned short Al[64*256], Bl[64*256];
  const int at = blockIdx.x, bt = blockIdx.y, b = blockIdx.z;
  const int a0 = at*64, o0 = bt*64;
  stage_64x256(Al, Ag + ((size_t)(b*4096 + a0))*256, 256);
  stage_64x256(Bl, Bg + (size_t)o0*256, 256);
  __syncthreads();
  const int t = threadIdx.x, w = t>>6, lane = t&63, lam = lane&15, lg = lane>>4;
  f32x4 zz = {0.f,0.f,0.f,0.f};
  f32x4 acc[4] = {zz,zz,zz,zz};
  #pragma unroll
  for (int u=0;u<8;++u){
    int ar = 16*w + lam;
    s16x8 af = *(const s16x8*)((const char*)Al + ar*512 + ((64*u+16*lg) ^ ((ar&7)<<4)));
    #pragma unroll
    for (int ct=0;ct<4;++ct){
      int br = 16*ct + lam;
      s16x8 bf = *(const s16x8*)((const char*)Bl + br*512 + ((64*u+16*lg) ^ ((br&7)<<4)));
      acc[ct] = MFMA16(af, bf, acc[ct]);
    }
  }
  #pragma unroll
  for (int ct=0;ct<4;++ct){
    int o = o0 + 16*ct + lam;
    float ob_ = biasg[o];
    size_t base = ((size_t)(b*256 + o))*4096 + a0 + 16*w + 4*lg;
    f32x4 xv = *(const f32x4*)(xg + base);
    f32x4 ov;
    #pragma unroll
    for (int r=0;r<4;++r) ov[r] = acc[ct][r] + ob_ + xv[r];
    *(f32x4*)(outg + base) = ov;
  }
}

extern "C" void kernel_launch(void* const* d_in, const int* in_sizes, int n_in,
                              void* d_out, int out_size, void* d_ws, size_t ws_size,
                              hipStream_t stream){
  const float* x     = (const float*)d_in[0];
  const float* qkv_w = (const float*)d_in[1];
  const float* qkv_b = (const float*)d_in[2];
  const float* out_w = (const float*)d_in[3];
  const float* out_b = (const float*)d_in[4];
  const float* d1_w  = (const float*)d_in[5];
  const float* d1_b  = (const float*)d_in[6];
  const float* d2_w  = (const float*)d_in[7];
  const float* d2_b  = (const float*)d_in[8];
  float* out = (float*)d_out;

  char* p = (char*)d_ws;
  const size_t BIG = (size_t)8*4096*256*2;
  unsigned short* Xt = (unsigned short*)p; p += BIG;   // reused as AOt after QKV GEMM
  unsigned short* Q  = (unsigned short*)p; p += BIG;
  unsigned short* K  = (unsigned short*)p; p += BIG;
  unsigned short* Vt = (unsigned short*)p; p += BIG;
  unsigned short* Wq = (unsigned short*)p; p += (size_t)768*256*2;
  unsigned short* Wo = (unsigned short*)p; p += (size_t)256*256*2;
  float* gray = (float*)p; p += (size_t)8*4096*4;
  float* labs = (float*)p; p += (size_t)8*4096*4;
  float* hbuf = (float*)p; p += (size_t)8*8*4096*4;
  float* sc   = (float*)p; p += (size_t)8*4096*4;

  k_cvt      <<<dim3(192),    256, 0, stream>>>(qkv_w, Wq);
  k_cvt      <<<dim3(64),     256, 0, stream>>>(out_w, Wo);
  k_transpose<<<dim3(64,4,8), 256, 0, stream>>>(x, Xt);
  k_gray     <<<dim3(16,8),   256, 0, stream>>>(x, gray);
  k_lapabs   <<<dim3(16,8),   256, 0, stream>>>(gray, labs);
  k_h8       <<<dim3(16,8),   256, 0, stream>>>(labs, d1_w, d1_b, hbuf);
  k_scale    <<<dim3(16,8),   256, 0, stream>>>(hbuf, d2_w, d2_b, sc);
  k_gemm_qkv <<<dim3(64,12,8),256, 0, stream>>>(Wq, Xt, qkv_b, Q, K, Vt);
  k_attn     <<<dim3(256),    256, 0, stream>>>(Q, K, Vt, sc, Xt);
  k_gemm_out <<<dim3(64,4,8), 256, 0, stream>>>(Xt, Wo, out_b, x, out);
}